// Round 1
// baseline (140.036 us; speedup 1.0000x reference)
//
#include <hip/hip_runtime.h>
#include <hip/hip_bf16.h>
#include <stdint.h>

// Problem constants (fixed by setup_inputs)
#define M_N  16384   // batch rows
#define K_C  2048    // centers
#define DIM  512     // feature dim
#define NCLS 10      // classes
#define NBN  8       // center-blocks (K_C/256) -> split-K partials
#define BKK  64      // K-step
#define NSTEP (DIM / BKK)   // 8

typedef unsigned short u16;
typedef float  f32x4  __attribute__((ext_vector_type(4)));
typedef __bf16 bf16x8 __attribute__((ext_vector_type(8)));

// ---- helpers -------------------------------------------------------------

__device__ __forceinline__ void async_ld16(const void* g, void* l) {
  // global -> LDS direct DMA, 16 bytes per lane. LDS dest is wave-uniform
  // base + lane*16 -- swizzle must be on the SOURCE.
  __builtin_amdgcn_global_load_lds(
      (const __attribute__((address_space(1))) void*)g,
      (__attribute__((address_space(3))) void*)l,
      16, 0, 0);
}

__device__ __forceinline__ u16 f2bf_rne(float f) {
  uint32_t u = __float_as_uint(f);
  u += 0x7FFFu + ((u >> 16) & 1u);
  return (u16)(u >> 16);
}

// ---- kernel 1: prep (batches/centers -> bf16 + norms, W -> Wperm bf16) ---
// UNCHANGED from previous round. Wperm's permutation is per-128-center
// block, so it is reused unchanged by the 256-wide tiles (cblk = bn*2+wr).

#define NPREP ((M_N + K_C) / 2)

__global__ __launch_bounds__(256) void prep(
    const float4* __restrict__ batches, const float4* __restrict__ centers,
    const float* __restrict__ W,
    ushort4* __restrict__ Abf, ushort4* __restrict__ Bbf,
    float* __restrict__ x2, float* __restrict__ c2, u16* __restrict__ Wperm) {
  int b = blockIdx.x, t = threadIdx.x;
  if (b < NPREP) {
    int rp = b * 2 + (t >> 7);          // row index (pair)
    int col = t & 127;
    const float4* src; ushort4* dst; float* sq; int row;
    if (rp < M_N) { src = batches; dst = Abf; sq = x2; row = rp; }
    else          { src = centers; dst = Bbf; sq = c2; row = rp - M_N; }
    float4 v = src[(size_t)row * 128 + col];
    float ss = v.x * v.x + v.y * v.y + v.z * v.z + v.w * v.w;
    ushort4 o;
    o.x = f2bf_rne(v.x); o.y = f2bf_rne(v.y);
    o.z = f2bf_rne(v.z); o.w = f2bf_rne(v.w);
    dst[(size_t)row * 128 + col] = o;
    ss += __shfl_down(ss, 32);
    ss += __shfl_down(ss, 16);
    ss += __shfl_down(ss, 8);
    ss += __shfl_down(ss, 4);
    ss += __shfl_down(ss, 2);
    ss += __shfl_down(ss, 1);
    __shared__ float part[4];
    if ((t & 63) == 0) part[t >> 6] = ss;
    __syncthreads();
    if (t == 0) sq[row] = part[0] + part[1];
    if (t == 128) sq[row] = part[2] + part[3];
  } else {
    int wb = b - NPREP;                 // 32 blocks x 1024 elems
#pragma unroll
    for (int i = 0; i < 4; ++i) {
      int p = wb * 1024 + i * 256 + t;  // < 16*2048
      int cls = p >> 11, k = p & 2047;
      int bn = k >> 7, rem = k & 127;
      int hh = (rem >> 6) & 1, tt = (rem >> 5) & 1;
      int qq = (rem >> 3) & 3, jj = rem & 7;
      int c = bn * 128 + hh * 64 + (tt * 2 + (jj >> 2)) * 16 + qq * 4 + (jj & 3);
      Wperm[p] = (cls < NCLS) ? f2bf_rne(W[cls * K_C + c]) : (u16)0;
    }
  }
}

// ---- kernel 2: 8-phase 256x256 fused xc-GEMM -> radial -> radial@Wperm^T -
//
// Port of the validated 256^2 8-phase counted-vmcnt template (T3+T4+T5 on
// top of the existing T2 source-swizzle). 512 threads = 8 waves (wr = 2
// center-halves of 128, wc = 4 batch-quarters of 64). BK=64, 8 K-steps.
// LDS 128 KiB: 2 bufs x {A(centers) 256x64, B(batches) 256x64} bf16, each
// operand as 2 half-regions of [128][64], XOR-chunk-swizzled.
//
// Per K-step: 4 phases, quadrant order (0,0),(0,1),(1,1),(1,0):
//   ph1: ds_read A-mh0 (8xb128) + B-nh0 (4)  | MFMA m0-3 x n0-1
//   ph2: ds_read B-nh1 (4)                   | MFMA m0-3 x n2-3
//   ph3: ds_read A-mh1 (8) + STAGE(t+2).B    | MFMA m4-7 x n2-3
//   ph4: STAGE(t+2).A, MFMA m4-7 x n0-1, s_waitcnt vmcnt(8)
// Zero-race staging: B regions last ds_read at ph2, staged at ph3; A last
// read at ph3, staged at ph4 -- always >= 1 full barrier after the last
// read completes (reads complete before that phase's MFMA lgkm-wait, which
// precedes its closing barrier). vmcnt(8) leaves exactly step t+2's 8
// loads/thread in flight; drained at ph4 of the following step, one full
// K-step before first use. NO __syncthreads in the loop (it would emit
// vmcnt(0) and recreate the 2-phase drain this rewrite removes).

#define SB0 __builtin_amdgcn_sched_barrier(0)

#define PH_OPEN_LGKM do { SB0; __builtin_amdgcn_s_barrier(); \
    asm volatile("s_waitcnt lgkmcnt(0)" ::: "memory"); SB0; } while (0)
#define PH_OPEN      do { SB0; __builtin_amdgcn_s_barrier(); SB0; } while (0)
#define PH_CLOSE     do { SB0; __builtin_amdgcn_s_barrier(); SB0; } while (0)

#define MFMA_Q(MB, NB) do { \
    __builtin_amdgcn_s_setprio(1); \
    _Pragma("unroll") for (int mm = 0; mm < 4; ++mm) \
    _Pragma("unroll") for (int nn = 0; nn < 2; ++nn) \
    _Pragma("unroll") for (int kh = 0; kh < 2; ++kh) \
      acc[(MB) + mm][(NB) + nn] = __builtin_amdgcn_mfma_f32_16x16x32_bf16( \
          cfA[mm][kh], bfB[(NB) + nn][kh], acc[(MB) + mm][(NB) + nn], 0, 0, 0); \
    __builtin_amdgcn_s_setprio(0); \
  } while (0)

// stage one operand of K-step tt into buf[tt&1]: 4 x global_load_lds /thread
#define STAGE_A(tt) do { \
    _Pragma("unroll") for (int h = 0; h < 2; ++h) \
    _Pragma("unroll") for (int j = 0; j < 2; ++j) \
      async_ld16(cSrc + (size_t)(h * 128 + j * 64) * DIM + (tt) * BKK, \
                 smA + ((tt) & 1) * 65536 + h * 16384 + j * 8192 + tid * 16); \
  } while (0)
#define STAGE_B(tt) do { \
    _Pragma("unroll") for (int h = 0; h < 2; ++h) \
    _Pragma("unroll") for (int j = 0; j < 2; ++j) \
      async_ld16(bSrc + (size_t)(h * 128 + j * 64) * DIM + (tt) * BKK, \
                 smB + ((tt) & 1) * 65536 + h * 16384 + j * 8192 + tid * 16); \
  } while (0)

__global__ __launch_bounds__(512, 2) void rbf_main(
    const u16* __restrict__ bat,    // bf16 bits [M_N][DIM]  (batches)
    const u16* __restrict__ cen,    // bf16 bits [K_C][DIM]  (centers)
    const float* __restrict__ x2,   // [M_N]
    const float* __restrict__ c2,   // [K_C]
    const float* __restrict__ beta, // [K_C]
    const u16* __restrict__ Wperm,  // bf16 bits [16][K_C] permuted
    float* __restrict__ partial) {  // [NBN][M_N][16]
  __shared__ alignas(16) char smem[131072];

  const int tid  = threadIdx.x;
  const int lane = tid & 63;
  const int wid  = tid >> 6;
  const int wr   = wid >> 2;        // center half: 128 centers
  const int wc   = wid & 3;         // batch quarter: 64 batches

  // XCD-contiguous swizzle: 512 wgs over 8 XCDs -> XCD x gets bm [8x,8x+8)
  const int bid = blockIdx.x;
  const int swz = (bid & 7) * 64 + (bid >> 3);
  const int bm = swz >> 3;          // batch block  0..63
  const int bn = swz & 7;           // center block 0..7
  const int rb0 = bm * 256;
  const int cb0 = bn * 256;

  // staging: thread t -> LDS row (t>>3)+j*64, chunk t&7; source chunk
  // pre-swizzled so LDS[r][c ^ (r&7)] = global (r, chunk c).
  const int srow = tid >> 3;
  const int swzc = (tid & 7) ^ (srow & 7);
  const u16* cSrc = cen + (size_t)(cb0 + srow) * DIM + swzc * 8;
  const u16* bSrc = bat + (size_t)(rb0 + srow) * DIM + swzc * 8;
  char* smA = smem;
  char* smB = smem + 32768;

  // MFMA fragment read addressing
  const int frow = lane & 15;       // operand row within 16-strip
  const int fq   = lane >> 4;       // k-quarter
  const int fsw  = frow & 7;
  const int ck0  = ((0 + fq) ^ fsw) * 16;   // kh=0 swizzled chunk (bytes)
  const int ck1  = ((4 + fq) ^ fsw) * 16;   // kh=1
  const char* aRd = smem + wr * 16384 + frow * 128;
  const char* bRd = smem + 32768 + (wc >> 1) * 16384 + (wc & 1) * 8192 + frow * 128;

  f32x4 acc[8][4] = {};   // acc[m = center strip 0..7][n = batch strip 0..3]

  // ---- prologue: stage steps 0,1; wait step 0 landed (8 newest in flight)
  STAGE_B(0); STAGE_A(0); STAGE_B(1); STAGE_A(1);
  asm volatile("s_waitcnt vmcnt(8)" ::: "memory");
  __builtin_amdgcn_s_barrier();
  SB0;

  // ---- main loop: 8 K-steps x 4 phases ----
#pragma unroll
  for (int t = 0; t < NSTEP; ++t) {
    const char* Ab = aRd + (t & 1) * 65536;
    const char* Bb = bRd + (t & 1) * 65536;
    bf16x8 cfA[4][2], bfB[4][2];

    // phase 1: A-mh0 + B-nh0 reads; MFMA quad (m0-3, n0-1)
#pragma unroll
    for (int m = 0; m < 4; ++m) {
      cfA[m][0] = *(const bf16x8*)(Ab + m * 2048 + ck0);
      cfA[m][1] = *(const bf16x8*)(Ab + m * 2048 + ck1);
    }
#pragma unroll
    for (int n = 0; n < 2; ++n) {
      bfB[n][0] = *(const bf16x8*)(Bb + n * 2048 + ck0);
      bfB[n][1] = *(const bf16x8*)(Bb + n * 2048 + ck1);
    }
    PH_OPEN_LGKM;
    MFMA_Q(0, 0);
    PH_CLOSE;

    // phase 2: B-nh1 reads; MFMA quad (m0-3, n2-3). B regions retire here.
#pragma unroll
    for (int n = 2; n < 4; ++n) {
      bfB[n][0] = *(const bf16x8*)(Bb + n * 2048 + ck0);
      bfB[n][1] = *(const bf16x8*)(Bb + n * 2048 + ck1);
    }
    PH_OPEN_LGKM;
    MFMA_Q(0, 2);
    PH_CLOSE;

    // phase 3: A-mh1 reads (reuse cfA regs); stage (t+2).B into retired
    // B regions of this buffer; MFMA quad (m4-7, n2-3). A retires here.
#pragma unroll
    for (int m = 0; m < 4; ++m) {
      cfA[m][0] = *(const bf16x8*)(Ab + 8192 + m * 2048 + ck0);
      cfA[m][1] = *(const bf16x8*)(Ab + 8192 + m * 2048 + ck1);
    }
    if (t < NSTEP - 2) STAGE_B(t + 2);
    PH_OPEN_LGKM;
    MFMA_Q(4, 2);
    PH_CLOSE;

    // phase 4: stage (t+2).A; MFMA quad (m4-7, n0-1) from registers;
    // counted vmcnt (drains step t+1, leaves step t+2's 8 loads in flight)
    if (t < NSTEP - 2) STAGE_A(t + 2);
    PH_OPEN;
    MFMA_Q(4, 0);
    SB0;
    if (t < NSTEP - 2) {
      asm volatile("s_waitcnt vmcnt(8)" ::: "memory");
    } else if (t == NSTEP - 2) {
      asm volatile("s_waitcnt vmcnt(0)" ::: "memory");
    }
    __builtin_amdgcn_s_barrier();
    SB0;
  }

  // ---- epilogue: acc (xc) -> radial, IN PLACE ----
  // D layout: col(lane&15)=batch within strip, row(q*4+reg)=center.
  const int cls = frow, q = fq;
  float4 c2q[8], btq[8];
#pragma unroll
  for (int m = 0; m < 8; ++m) {
    int base = cb0 + wr * 128 + m * 16 + q * 4;   // 4 consecutive centers
    c2q[m] = *(const float4*)(c2 + base);
    btq[m] = *(const float4*)(beta + base);
  }
  float x2v[4];
#pragma unroll
  for (int n = 0; n < 4; ++n)
    x2v[n] = x2[rb0 + wc * 64 + n * 16 + cls];

#pragma unroll
  for (int m = 0; m < 8; ++m)
#pragma unroll
    for (int n = 0; n < 4; ++n)
#pragma unroll
      for (int r = 0; r < 4; ++r) {
        float xc = acc[m][n][r];
        float d2 = fmaxf(x2v[n] + c2q[m][r] - 2.0f * xc, 0.0f);
        acc[m][n][r] = __expf(-btq[m][r] * sqrtf(d2));
      }

  // ---- stage 2: wave's 128 centers (2 permuted 128-blocks? no: 1 block
  // of 128 = cblk) vs Wperm. Register order matches Wperm permutation.
  const int cblk = bn * 2 + wr;     // 128-center block index
  bf16x8 wfr[2][2];
#pragma unroll
  for (int h = 0; h < 2; ++h)
#pragma unroll
    for (int tt = 0; tt < 2; ++tt)
      wfr[h][tt] = *(const bf16x8*)(Wperm + (size_t)cls * K_C + cblk * 128 +
                                    h * 64 + tt * 32 + q * 8);

  f32x4 acc2[4] = {};
#pragma unroll
  for (int n = 0; n < 4; ++n)
#pragma unroll
    for (int h = 0; h < 2; ++h)
#pragma unroll
      for (int tt = 0; tt < 2; ++tt) {
        union { u16 hh[8]; bf16x8 v; } pk;
#pragma unroll
        for (int r = 0; r < 4; ++r) {
          pk.hh[r]     = f2bf_rne(acc[h * 4 + 2 * tt][n][r]);
          pk.hh[4 + r] = f2bf_rne(acc[h * 4 + 2 * tt + 1][n][r]);
        }
        acc2[n] = __builtin_amdgcn_mfma_f32_16x16x32_bf16(
            pk.v, wfr[h][tt], acc2[n], 0, 0, 0);
      }

  // ---- wave-pair sum (wr=0 and wr=1 share batches, split centers) ----
  // staging LDS dead (all loop reads done before final barrier); reuse.
  f32x4* sumbuf = (f32x4*)smem;
  if (wr == 1) {
#pragma unroll
    for (int n = 0; n < 4; ++n)
      sumbuf[(wc * 4 + n) * 64 + lane] = acc2[n];
  }
  __syncthreads();
  if (wr == 0) {
#pragma unroll
    for (int n = 0; n < 4; ++n) {
      f32x4 o = sumbuf[(wc * 4 + n) * 64 + lane];
      acc2[n] += o;
      // D2: col(lane&15)=class, row(q*4+r)=batch row within strip.
#pragma unroll
      for (int r = 0; r < 4; ++r) {
        int gr = rb0 + wc * 64 + n * 16 + q * 4 + r;
        __builtin_nontemporal_store(
            acc2[n][r], &partial[((size_t)bn * M_N + gr) * 16 + cls]);
      }
    }
  }
}

// ---- kernel 3: out[i][:] = b + sum_bn partial[bn][i][:] ------------------

__global__ __launch_bounds__(256) void reduce_out(
    const float* __restrict__ partial, const float* __restrict__ b,
    float* __restrict__ out) {
  int t = threadIdx.x;
  int row = blockIdx.x * 64 + (t >> 2);
  int quad = t & 3;
  f32x4 v = {0.f, 0.f, 0.f, 0.f};
#pragma unroll
  for (int bn = 0; bn < NBN; ++bn) {
    f32x4 p = __builtin_nontemporal_load(
        (const f32x4*)(partial + ((size_t)bn * M_N + row) * 16 + quad * 4));
    v += p;
  }
  if (quad == 0) {
    float4 bq = *(const float4*)b;
    float* o = out + (size_t)row * NCLS;
    *(float2*)o       = {v.x + bq.x, v.y + bq.y};
    *(float2*)(o + 2) = {v.z + bq.z, v.w + bq.w};
  } else if (quad == 1) {
    float4 bq = *(const float4*)(b + 4);
    float* o = out + (size_t)row * NCLS + 4;
    *(float2*)o       = {v.x + bq.x, v.y + bq.y};
    *(float2*)(o + 2) = {v.z + bq.z, v.w + bq.w};
  } else if (quad == 2) {
    *(float2*)(out + (size_t)row * NCLS + 8) = {v.x + b[8], v.y + b[9]};
  }
}

// ---- launch --------------------------------------------------------------

extern "C" void kernel_launch(void* const* d_in, const int* in_sizes, int n_in,
                              void* d_out, int out_size, void* d_ws, size_t ws_size,
                              hipStream_t stream) {
  const float* batches = (const float*)d_in[0];  // [16384,512]
  const float* centers = (const float*)d_in[1];  // [2048,512]
  const float* beta    = (const float*)d_in[2];  // [1,2048]
  const float* W       = (const float*)d_in[3];  // [10,2048]
  const float* bias    = (const float*)d_in[4];  // [10]
  float* out = (float*)d_out;                    // [16384,10]

  char* ws = (char*)d_ws;
  u16*  Abf = (u16*)ws;                                   // 16 MiB batches
  u16*  Bbf = (u16*)(ws + (size_t)M_N * DIM * 2);         // 2 MiB centers
  float* x2 = (float*)(ws + (size_t)(M_N + K_C) * DIM * 2);
  float* c2 = x2 + M_N;
  u16*  Wpm = (u16*)(c2 + K_C);                           // 64 KiB
  float* partial = (float*)((char*)Wpm + 16 * K_C * 2);   // 8.4 MiB

  prep<<<dim3(NPREP + 32), dim3(256), 0, stream>>>(
      (const float4*)batches, (const float4*)centers, W,
      (ushort4*)Abf, (ushort4*)Bbf, x2, c2, Wpm);
  rbf_main<<<dim3(512), dim3(512), 0, stream>>>(
      Abf, Bbf, x2, c2, beta, Wpm, partial);
  reduce_out<<<dim3(M_N / 64), dim3(256), 0, stream>>>(partial, bias, out);
}